// Round 25
// baseline (310.964 us; speedup 1.0000x reference)
//
#include <hip/hip_runtime.h>
#include <hip/hip_bf16.h>
#include <hip/hip_fp16.h>

// SASA local self-attention, fused. Round 22 kernel, 3rd resubmit (container died 3x):
//  r21 + sched_barrier(0) per ki-row.
//  The 56-position unrolled online-softmax loop has a serial (m,d) chain; the
//  scheduler hoisted ALL 56x8 dwords of LDS loads above it -> 1.77KB/thread
//  scratch (= the measured 464MB WRITE). sched_barrier(0) after each ki row
//  caps the window at 8 positions (64 dwords) with static indexing intact.
// B=4, CIN=COUT=256, H=W=64, G=8, CG=32, K=7, PAD=3.
#define TS   16
#define HS   22
#define HP   484
#define KDW  18          // u32 stride per halo pixel (72B, 8B-aligned)
#define KK   7

typedef _Float16 h2 __attribute__((ext_vector_type(2)));
union U32H { unsigned u; h2 h; __half2 p; };

__device__ __forceinline__ h2 pkrtz(float a, float b) {
    auto r = __builtin_amdgcn_cvt_pkrtz(a, b);
    union { decltype(r) i; h2 o; } c; c.i = r;
    return c.o;
}
__device__ __forceinline__ float dot2(h2 a, h2 b, float c) {
#if __has_builtin(__builtin_amdgcn_fdot2)
    return __builtin_amdgcn_fdot2(a, b, c, false);
#else
    return fmaf((float)a.x, (float)b.x, fmaf((float)a.y, (float)b.y, c));
#endif
}
__device__ __forceinline__ float dot2u(unsigned wu, h2 b, float c) {
    U32H w; w.u = wu; return dot2(w.h, b, c);
}
__device__ __forceinline__ float qswap1(float v) {
#if __has_builtin(__builtin_amdgcn_mov_dpp)
    return __int_as_float(__builtin_amdgcn_mov_dpp(__float_as_int(v), 0xB1, 0xF, 0xF, true));
#else
    return __shfl_xor(v, 1, 64);
#endif
}
__device__ __forceinline__ float qswap2(float v) {
#if __has_builtin(__builtin_amdgcn_mov_dpp)
    return __int_as_float(__builtin_amdgcn_mov_dpp(__float_as_int(v), 0x4E, 0xF, 0xF, true));
#else
    return __shfl_xor(v, 2, 64);
#endif
}
__device__ __forceinline__ void sbar() {
#if __has_builtin(__builtin_amdgcn_sched_barrier)
    __builtin_amdgcn_sched_barrier(0);
#endif
}

__global__ __attribute__((amdgpu_flat_work_group_size(512, 512), amdgpu_waves_per_eu(4, 4)))
void sasa_fused_kernel(const float* __restrict__ x,
                       const float* __restrict__ wq,
                       const float* __restrict__ wk,
                       const float* __restrict__ wv,
                       const float* __restrict__ row_emb,
                       const float* __restrict__ col_emb,
                       float* __restrict__ out)
{
    __shared__ h2       s_w[1536];         // [m(k,v,q)*2+hh][cp][co], 6 KB
    __shared__ float    s_emb[224];        // E[c][t], 0.9 KB
    __shared__ unsigned s_ku[HP * KDW];    // K halo, f16 pairs, 34.8 KB
    __shared__ unsigned s_vu[HP * KDW];    // V halo, f16 pairs, 34.8 KB

    const int tid = threadIdx.x;

    // ---- XCD-bijective swizzle (r15) ----
    const int lin  = blockIdx.x + (blockIdx.y << 2) + (blockIdx.z << 4);
    const int xcd  = lin & 7;
    const int slot = lin >> 3;
    const int zg   = xcd + ((slot >> 4) << 3);
    const int sp   = slot & 15;
    const int b    = zg >> 3;
    const int g    = zg & 7;
    const int y0   = (sp >> 2) * TS;
    const int x0   = (sp & 3) * TS;

    const float* xg = x + (size_t)(b * 256 + g * 32) * 4096;

    // ---- pre-issue projection x loads, h2-converted at load ----
    const int hh0 = (tid >= HP) ? 1 : 0;
    const int hp0 = tid - (hh0 ? HP : 0);
    const int hy0 = hp0 / HS, hx0 = hp0 - hy0 * HS;
    const int gy0 = y0 + hy0 - 3, gx0 = x0 + hx0 - 3;
    const bool ok0 = ((unsigned)gy0 < 64u) && ((unsigned)gx0 < 64u);

    const int hp1 = tid + 28;
    const int hy1 = hp1 / HS, hx1 = hp1 - hy1 * HS;
    const int gy1 = y0 + hy1 - 3, gx1 = x0 + hx1 - 3;
    const bool it1v = (tid < 2 * HP - 512);
    const bool ok1 = it1v && ((unsigned)gy1 < 64u) && ((unsigned)gx1 < 64u);

    h2 x0h[16], x1h[16];
    {
        const h2 z = pkrtz(0.f, 0.f);
        #pragma unroll
        for (int cp = 0; cp < 16; ++cp) { x0h[cp] = z; x1h[cp] = z; }
    }
    if (ok0) {
        const float* xp = xg + gy0 * 64 + gx0;
        #pragma unroll
        for (int cp = 0; cp < 16; ++cp)
            x0h[cp] = pkrtz(xp[(2 * cp) * 4096], xp[(2 * cp + 1) * 4096]);
    }
    if (ok1) {
        const float* xp = xg + gy1 * 64 + gx1;
        #pragma unroll
        for (int cp = 0; cp < 16; ++cp)
            x1h[cp] = pkrtz(xp[(2 * cp) * 4096], xp[(2 * cp + 1) * 4096]);
    }

    // ---- stage weights (f16) + emb (f32) ----
    {
        const int cp  = tid & 15;
        const int cog = tid >> 4;
        const int hh  = cog >> 4;
        const int co  = cog & 15;
        const int di  = (hh * 16 + cp) * 16 + co;
        const float2* wk2 = (const float2*)(wk + g * 1024);
        const float2* wv2 = (const float2*)(wv + g * 1024);
        const float2* wq2 = (const float2*)(wq + g * 1024);
        float2 a = wk2[tid]; s_w[di]        = pkrtz(a.x, a.y);
        float2 v = wv2[tid]; s_w[512 + di]  = pkrtz(v.x, v.y);
        float2 q = wq2[tid]; s_w[1024 + di] = pkrtz(q.x, q.y);
    }
    if (tid < 224) {
        int c = tid / KK, t = tid - c * KK;
        s_emb[tid] = (g < 4) ? row_emb[(g * 32 + c) * KK + t]
                             : col_emb[((g - 4) * 32 + c) * KK + t];
    }
    __syncthreads();

    // ---- projection item0 ----
    {
        float accK[16], accV[16];
        #pragma unroll
        for (int c = 0; c < 16; ++c) { accK[c] = 0.f; accV[c] = 0.f; }
        const h2* wkp = s_w + hh0 * 256;
        const h2* wvp = s_w + 512 + hh0 * 256;
        #pragma unroll
        for (int cp = 0; cp < 16; ++cp) {
            h2 xv = x0h[cp];
            const uint4* wkr = (const uint4*)(wkp + cp * 16);
            const uint4* wvr = (const uint4*)(wvp + cp * 16);
            uint4 kw[4] = { wkr[0], wkr[1], wkr[2], wkr[3] };
            uint4 vw[4] = { wvr[0], wvr[1], wvr[2], wvr[3] };
            const unsigned* kwu = (const unsigned*)kw;
            const unsigned* vwu = (const unsigned*)vw;
            #pragma unroll
            for (int co = 0; co < 16; ++co) {
                accK[co] = dot2u(kwu[co], xv, accK[co]);
                accV[co] = dot2u(vwu[co], xv, accV[co]);
            }
        }
        unsigned* dk = s_ku + hp0 * KDW + hh0 * 8;
        unsigned* dv = s_vu + hp0 * KDW + hh0 * 8;
        #pragma unroll
        for (int j = 0; j < 4; ++j) {
            U32H a0, a1, b0, b1;
            a0.h = pkrtz(accK[4 * j],     accK[4 * j + 1]);
            a1.h = pkrtz(accK[4 * j + 2], accK[4 * j + 3]);
            b0.h = pkrtz(accV[4 * j],     accV[4 * j + 1]);
            b1.h = pkrtz(accV[4 * j + 2], accV[4 * j + 3]);
            ((uint2*)dk)[j] = make_uint2(a0.u, a1.u);
            ((uint2*)dv)[j] = make_uint2(b0.u, b1.u);
        }
    }
    // ---- projection item1 (hh=1) ----
    if (it1v) {
        float accK[16], accV[16];
        #pragma unroll
        for (int c = 0; c < 16; ++c) { accK[c] = 0.f; accV[c] = 0.f; }
        const h2* wkp = s_w + 256;
        const h2* wvp = s_w + 512 + 256;
        #pragma unroll
        for (int cp = 0; cp < 16; ++cp) {
            h2 xv = x1h[cp];
            const uint4* wkr = (const uint4*)(wkp + cp * 16);
            const uint4* wvr = (const uint4*)(wvp + cp * 16);
            uint4 kw[4] = { wkr[0], wkr[1], wkr[2], wkr[3] };
            uint4 vw[4] = { wvr[0], wvr[1], wvr[2], wvr[3] };
            const unsigned* kwu = (const unsigned*)kw;
            const unsigned* vwu = (const unsigned*)vw;
            #pragma unroll
            for (int co = 0; co < 16; ++co) {
                accK[co] = dot2u(kwu[co], xv, accK[co]);
                accV[co] = dot2u(vwu[co], xv, accV[co]);
            }
        }
        unsigned* dk = s_ku + hp1 * KDW + 8;
        unsigned* dv = s_vu + hp1 * KDW + 8;
        #pragma unroll
        for (int j = 0; j < 4; ++j) {
            U32H a0, a1, b0, b1;
            a0.h = pkrtz(accK[4 * j],     accK[4 * j + 1]);
            a1.h = pkrtz(accK[4 * j + 2], accK[4 * j + 3]);
            b0.h = pkrtz(accV[4 * j],     accV[4 * j + 1]);
            b1.h = pkrtz(accV[4 * j + 2], accV[4 * j + 3]);
            ((uint2*)dk)[j] = make_uint2(a0.u, a1.u);
            ((uint2*)dv)[j] = make_uint2(b0.u, b1.u);
        }
    }

    // ---- attention mapping: thread = (pair pr, quarter h4) ----
    const int pr = tid >> 2;
    const int h4 = tid & 3;
    const int ty = pr >> 3;
    const int pc = pr & 7;
    const int x0l = pc * 2;
    const int yy  = y0 + ty;
    const int xxa = x0 + x0l;

    // ---- Q projection, h2-staged ----
    float qa[8], qb[8];
    #pragma unroll
    for (int j = 0; j < 8; ++j) { qa[j] = 0.f; qb[j] = 0.f; }
    {
        const float* xpa = xg + yy * 64 + xxa;
        h2 xa2[16], xb2[16];
        #pragma unroll
        for (int cp = 0; cp < 16; ++cp) {
            float2 v0 = *(const float2*)(xpa + (2 * cp) * 4096);
            float2 v1 = *(const float2*)(xpa + (2 * cp + 1) * 4096);
            xa2[cp] = pkrtz(v0.x, v1.x);
            xb2[cp] = pkrtz(v0.y, v1.y);
        }
        const h2* wqb = s_w + 1024 + ((h4 >> 1) * 16) * 16 + (h4 & 1) * 8;
        #pragma unroll
        for (int cp = 0; cp < 16; ++cp) {
            const uint4* wr = (const uint4*)(wqb + cp * 16);
            uint4 w0 = wr[0], w1 = wr[1];
            const unsigned* wu0 = (const unsigned*)&w0;
            const unsigned* wu1 = (const unsigned*)&w1;
            h2 va = xa2[cp], vb = xb2[cp];
            #pragma unroll
            for (int j = 0; j < 4; ++j) {
                qa[j]     = dot2u(wu0[j], va, qa[j]);
                qb[j]     = dot2u(wu0[j], vb, qb[j]);
                qa[4 + j] = dot2u(wu1[j], va, qa[4 + j]);
                qb[4 + j] = dot2u(wu1[j], vb, qb[4 + j]);
            }
        }
    }

    // ---- qe[7] per pixel over our 8 channels; quad-reduce to full sum ----
    float qea[KK], qeb[KK];
    #pragma unroll
    for (int t = 0; t < KK; ++t) {
        float aa = 0.f, ab = 0.f;
        #pragma unroll
        for (int j = 0; j < 8; ++j) {
            float e = s_emb[(h4 * 8 + j) * KK + t];
            aa = fmaf(qa[j], e, aa);
            ab = fmaf(qb[j], e, ab);
        }
        qea[t] = aa; qeb[t] = ab;
    }
    #pragma unroll
    for (int t = 0; t < KK; ++t) {
        qea[t] += qswap1(qea[t]); qea[t] += qswap2(qea[t]);
        qeb[t] += qswap1(qeb[t]); qeb[t] += qswap2(qeb[t]);
    }

    // ---- pack q ----
    h2 qa2[4], qb2[4];
    #pragma unroll
    for (int j = 0; j < 4; ++j) {
        qa2[j] = pkrtz(qa[2 * j], qa[2 * j + 1]);
        qb2[j] = pkrtz(qb[2 * j], qb[2 * j + 1]);
    }

    __syncthreads();   // s_ku / s_vu complete

    const int rowsel = (g < 4) ? 1 : 0;

    // ---- online-softmax over the 7x8 window union, sched-fenced per row ----
    float ma = -3.0e38f, da = 0.f, mb = -3.0e38f, db = 0.f;
    __half2 oa[4], ob[4];
    #pragma unroll
    for (int j = 0; j < 4; ++j) { oa[j] = __float2half2_rn(0.f); ob[j] = __float2half2_rn(0.f); }

    const unsigned* kbase = s_ku + h4 * 4;
    const unsigned* vbase = s_vu + h4 * 4;

    #pragma unroll
    for (int ki = 0; ki < KK; ++ki) {
        const int hprow = (ty + ki) * HS + x0l;
        #pragma unroll
        for (int c = 0; c < 8; ++c) {
            const int hp = hprow + c;
            const uint2* kp = (const uint2*)(kbase + hp * KDW);
            const uint2* vp = (const uint2*)(vbase + hp * KDW);
            uint2 k0 = kp[0], k1 = kp[1];
            uint2 v0 = vp[0], v1 = vp[1];

            float pa = 0.f, pb = 0.f;
            pa = dot2u(k0.x, qa2[0], pa);  pb = dot2u(k0.x, qb2[0], pb);
            pa = dot2u(k0.y, qa2[1], pa);  pb = dot2u(k0.y, qb2[1], pb);
            pa = dot2u(k1.x, qa2[2], pa);  pb = dot2u(k1.x, qb2[2], pb);
            pa = dot2u(k1.y, qa2[3], pa);  pb = dot2u(k1.y, qb2[3], pb);
            pa += qswap1(pa); pa += qswap2(pa);
            pb += qswap1(pb); pb += qswap2(pb);

            U32H c0, c1, c2, c3;
            c0.u = v0.x; c1.u = v0.y; c2.u = v1.x; c3.u = v1.y;

            if (c < 7) {   // pixel a: kj = c
                float lg = pa + (rowsel ? qea[ki] : qea[c]);
                float pmx  = fmaxf(ma, lg);
                float corr = __expf(ma - pmx);
                float pe   = __expf(lg - pmx);
                da = fmaf(da, corr, pe);
                ma = pmx;
                __half2 pe2   = __float2half2_rn(pe);
                __half2 corr2 = __float2half2_rn(corr);
                oa[0] = __hfma2(c0.p, pe2, __hmul2(oa[0], corr2));
                oa[1] = __hfma2(c1.p, pe2, __hmul2(oa[1], corr2));
                oa[2] = __hfma2(c2.p, pe2, __hmul2(oa[2], corr2));
                oa[3] = __hfma2(c3.p, pe2, __hmul2(oa[3], corr2));
            }
            if (c > 0) {   // pixel b: kj = c-1
                float lg = pb + (rowsel ? qeb[ki] : qeb[c - 1]);
                float pmx  = fmaxf(mb, lg);
                float corr = __expf(mb - pmx);
                float pe   = __expf(lg - pmx);
                db = fmaf(db, corr, pe);
                mb = pmx;
                __half2 pe2   = __float2half2_rn(pe);
                __half2 corr2 = __float2half2_rn(corr);
                ob[0] = __hfma2(c0.p, pe2, __hmul2(ob[0], corr2));
                ob[1] = __hfma2(c1.p, pe2, __hmul2(ob[1], corr2));
                ob[2] = __hfma2(c2.p, pe2, __hmul2(ob[2], corr2));
                ob[3] = __hfma2(c3.p, pe2, __hmul2(ob[3], corr2));
            }
        }
        sbar();   // cap the scheduler window: no load hoisting across rows
    }

    // ---- write 2 pixels x 8 channels ----
    const float inva = 1.0f / da;
    const float invb = 1.0f / db;
    float* op = out + (size_t)(b * 256 + g * 32 + h4 * 8) * 4096 + yy * 64 + xxa;
    #pragma unroll
    for (int j = 0; j < 4; ++j) {
        float2 fa = __half22float2(oa[j]);
        float2 fb = __half22float2(ob[j]);
        op[(2 * j) * 4096]         = fa.x * inva;
        op[(2 * j + 1) * 4096]     = fa.y * inva;
        op[(2 * j) * 4096 + 1]     = fb.x * invb;
        op[(2 * j + 1) * 4096 + 1] = fb.y * invb;
    }
}

extern "C" void kernel_launch(void* const* d_in, const int* in_sizes, int n_in,
                              void* d_out, int out_size, void* d_ws, size_t ws_size,
                              hipStream_t stream) {
    const float* x       = (const float*)d_in[0];
    const float* wq      = (const float*)d_in[1];
    const float* wk      = (const float*)d_in[2];
    const float* wv      = (const float*)d_in[3];
    const float* row_emb = (const float*)d_in[4];
    const float* col_emb = (const float*)d_in[5];
    float* out = (float*)d_out;

    dim3 grid(4, 4, 32);   // remapped inside kernel (XCD-bijective swizzle)
    dim3 block(512);
    sasa_fused_kernel<<<grid, block, 0, stream>>>(x, wq, wk, wv, row_emb, col_emb, out);
}

// Round 26
// 54.341 us; speedup vs baseline: 5.7225x; 5.7225x over previous
//
#include <hip/hip_runtime.h>
#include <hip/hip_bf16.h>
#include <hip/hip_fp16.h>

// SASA local self-attention, fused. Round 26: exact r16 (best-known, 49.9us)
// with ONE change: amdgpu_waves_per_eu(4,4) -> (2,2). Authorizes up to 256
// VGPRs so Phase A/PV can keep 8-12 independent LDS position-loads in flight
// (was ILP-starved at the 64-VGPR allocation). Trades TLP (16->8 waves/CU)
// for ILP on the diagnosed exposed-LDS-latency chain.
// B=4, CIN=COUT=256, H=W=64, G=8, CG=32, K=7, PAD=3.
#define TS   16
#define HS   22
#define HP   484
#define KDW  18          // u32 stride per halo pixel (72B)
#define KK   7
#define K2   49

typedef _Float16 h2 __attribute__((ext_vector_type(2)));
union U32H { unsigned u; h2 h; __half2 p; };

__device__ __forceinline__ h2 pkrtz(float a, float b) {
    auto r = __builtin_amdgcn_cvt_pkrtz(a, b);     // __fp16 vec2 on this clang
    union { decltype(r) i; h2 o; } c; c.i = r;     // same bits, retype
    return c.o;
}
__device__ __forceinline__ float dot2(h2 a, h2 b, float c) {
#if __has_builtin(__builtin_amdgcn_fdot2)
    return __builtin_amdgcn_fdot2(a, b, c, false);
#else
    return fmaf((float)a.x, (float)b.x, fmaf((float)a.y, (float)b.y, c));
#endif
}
__device__ __forceinline__ float dot2u(unsigned wu, h2 b, float c) {
    U32H w; w.u = wu; return dot2(w.h, b, c);
}
// v = value from lane^1 (quad_perm[1,0,3,2], VALU pipe, no LDS)
__device__ __forceinline__ float pswap(float v) {
#if __has_builtin(__builtin_amdgcn_mov_dpp)
    int j = __builtin_amdgcn_mov_dpp(__float_as_int(v), 0xB1, 0xF, 0xF, true);
    return __int_as_float(j);
#else
    return __shfl_xor(v, 1, 64);
#endif
}

__global__ __attribute__((amdgpu_flat_work_group_size(512, 512), amdgpu_waves_per_eu(2, 2)))
void sasa_fused_kernel(const float* __restrict__ x,
                       const float* __restrict__ wq,
                       const float* __restrict__ wk,
                       const float* __restrict__ wv,
                       const float* __restrict__ row_emb,
                       const float* __restrict__ col_emb,
                       float* __restrict__ out)
{
    __shared__ h2       s_w[1536];         // [m(k,v,q)*2+hh][cp][co], 6 KB
    __shared__ float    s_emb[224];        // E[c][t], 0.9 KB
    __shared__ unsigned s_ku[HP * KDW];    // K halo, f16 pairs, 34.8 KB
    __shared__ unsigned s_vu[HP * KDW];    // V halo, f16 pairs, 34.8 KB

    const int tid = threadIdx.x;

    // ---- XCD-bijective swizzle: 16 spatial tiles of each (b,g) share an XCD ----
    const int lin  = blockIdx.x + (blockIdx.y << 2) + (blockIdx.z << 4); // [0,512)
    const int xcd  = lin & 7;
    const int slot = lin >> 3;
    const int zg   = xcd + ((slot >> 4) << 3);
    const int sp   = slot & 15;
    const int b    = zg >> 3;
    const int g    = zg & 7;
    const int y0   = (sp >> 2) * TS;
    const int x0   = (sp & 3) * TS;

    const float* xg = x + (size_t)(b * 256 + g * 32) * 4096;

    // ---- pre-issue projection x loads (both items) ----
    const int hh0 = (tid >= HP) ? 1 : 0;
    const int hp0 = tid - (hh0 ? HP : 0);
    const int hy0 = hp0 / HS, hx0 = hp0 - hy0 * HS;
    const int gy0 = y0 + hy0 - 3, gx0 = x0 + hx0 - 3;
    const bool ok0 = ((unsigned)gy0 < 64u) && ((unsigned)gx0 < 64u);

    const int hp1 = tid + 28;
    const int hy1 = hp1 / HS, hx1 = hp1 - hy1 * HS;
    const int gy1 = y0 + hy1 - 3, gx1 = x0 + hx1 - 3;
    const bool it1v = (tid < 2 * HP - 512);
    const bool ok1 = it1v && ((unsigned)gy1 < 64u) && ((unsigned)gx1 < 64u);

    float xr0[32], xr1[32];
    #pragma unroll
    for (int ci = 0; ci < 32; ++ci) { xr0[ci] = 0.f; xr1[ci] = 0.f; }
    if (ok0) {
        const float* xp = xg + gy0 * 64 + gx0;
        #pragma unroll
        for (int ci = 0; ci < 32; ++ci) xr0[ci] = xp[ci * 4096];
    }
    if (ok1) {
        const float* xp = xg + gy1 * 64 + gx1;
        #pragma unroll
        for (int ci = 0; ci < 32; ++ci) xr1[ci] = xp[ci * 4096];
    }

    // ---- stage all 3 weight matrices as f16 pairs + emb slice ----
    {
        const int cp  = tid & 15;
        const int cog = tid >> 4;
        const int hh  = cog >> 4;
        const int co  = cog & 15;
        const int di  = (hh * 16 + cp) * 16 + co;
        const float2* wk2 = (const float2*)(wk + g * 1024);
        const float2* wv2 = (const float2*)(wv + g * 1024);
        const float2* wq2 = (const float2*)(wq + g * 1024);
        float2 a = wk2[tid]; s_w[di]        = pkrtz(a.x, a.y);
        float2 v = wv2[tid]; s_w[512 + di]  = pkrtz(v.x, v.y);
        float2 q = wq2[tid]; s_w[1024 + di] = pkrtz(q.x, q.y);
    }
    if (tid < 224) {
        int c = tid / KK, t = tid - c * KK;
        s_emb[tid] = (g < 4) ? row_emb[(g * 32 + c) * KK + t]
                             : col_emb[((g - 4) * 32 + c) * KK + t];
    }
    __syncthreads();

    // ---- item0 projection ----
    {
        h2 xv2[16];
        #pragma unroll
        for (int cp = 0; cp < 16; ++cp) xv2[cp] = pkrtz(xr0[2 * cp], xr0[2 * cp + 1]);
        float accK[16], accV[16];
        #pragma unroll
        for (int c = 0; c < 16; ++c) { accK[c] = 0.f; accV[c] = 0.f; }
        const h2* wkp = s_w + hh0 * 256;
        const h2* wvp = s_w + 512 + hh0 * 256;
        #pragma unroll
        for (int cp = 0; cp < 16; ++cp) {
            h2 xv = xv2[cp];
            const uint4* wkr = (const uint4*)(wkp + cp * 16);
            const uint4* wvr = (const uint4*)(wvp + cp * 16);
            uint4 kw[4] = { wkr[0], wkr[1], wkr[2], wkr[3] };
            uint4 vw[4] = { wvr[0], wvr[1], wvr[2], wvr[3] };
            const unsigned* kwu = (const unsigned*)kw;
            const unsigned* vwu = (const unsigned*)vw;
            #pragma unroll
            for (int co = 0; co < 16; ++co) {
                accK[co] = dot2u(kwu[co], xv, accK[co]);
                accV[co] = dot2u(vwu[co], xv, accV[co]);
            }
        }
        unsigned* dk = s_ku + hp0 * KDW + hh0 * 8;
        unsigned* dv = s_vu + hp0 * KDW + hh0 * 8;
        #pragma unroll
        for (int j = 0; j < 4; ++j) {
            U32H a0, a1, b0, b1;
            a0.h = pkrtz(accK[4 * j],     accK[4 * j + 1]);
            a1.h = pkrtz(accK[4 * j + 2], accK[4 * j + 3]);
            b0.h = pkrtz(accV[4 * j],     accV[4 * j + 1]);
            b1.h = pkrtz(accV[4 * j + 2], accV[4 * j + 3]);
            ((uint2*)dk)[j] = make_uint2(a0.u, a1.u);
            ((uint2*)dv)[j] = make_uint2(b0.u, b1.u);
        }
    }
    // ---- item1 projection (hh=1) ----
    if (it1v) {
        h2 xv2[16];
        #pragma unroll
        for (int cp = 0; cp < 16; ++cp) xv2[cp] = pkrtz(xr1[2 * cp], xr1[2 * cp + 1]);
        float accK[16], accV[16];
        #pragma unroll
        for (int c = 0; c < 16; ++c) { accK[c] = 0.f; accV[c] = 0.f; }
        const h2* wkp = s_w + 256;
        const h2* wvp = s_w + 512 + 256;
        #pragma unroll
        for (int cp = 0; cp < 16; ++cp) {
            h2 xv = xv2[cp];
            const uint4* wkr = (const uint4*)(wkp + cp * 16);
            const uint4* wvr = (const uint4*)(wvp + cp * 16);
            uint4 kw[4] = { wkr[0], wkr[1], wkr[2], wkr[3] };
            uint4 vw[4] = { wvr[0], wvr[1], wvr[2], wvr[3] };
            const unsigned* kwu = (const unsigned*)kw;
            const unsigned* vwu = (const unsigned*)vw;
            #pragma unroll
            for (int co = 0; co < 16; ++co) {
                accK[co] = dot2u(kwu[co], xv, accK[co]);
                accV[co] = dot2u(vwu[co], xv, accV[co]);
            }
        }
        unsigned* dk = s_ku + hp1 * KDW + 8;
        unsigned* dv = s_vu + hp1 * KDW + 8;
        #pragma unroll
        for (int j = 0; j < 4; ++j) {
            U32H a0, a1, b0, b1;
            a0.h = pkrtz(accK[4 * j],     accK[4 * j + 1]);
            a1.h = pkrtz(accK[4 * j + 2], accK[4 * j + 3]);
            b0.h = pkrtz(accV[4 * j],     accV[4 * j + 1]);
            b1.h = pkrtz(accV[4 * j + 2], accV[4 * j + 3]);
            ((uint2*)dk)[j] = make_uint2(a0.u, a1.u);
            ((uint2*)dv)[j] = make_uint2(b0.u, b1.u);
        }
    }

    // ---- q projection: thread (p, h) owns 16 q channels ----
    const int p  = tid >> 1;
    const int h  = tid & 1;
    const int tx = p & 15, ty = p >> 4;
    const int yy = y0 + ty, xx = x0 + tx;
    float accQ[16];
    #pragma unroll
    for (int c = 0; c < 16; ++c) accQ[c] = 0.f;
    {
        const float* xp = xg + yy * 64 + xx;
        h2 xv2[16];
        #pragma unroll
        for (int cp = 0; cp < 16; ++cp)
            xv2[cp] = pkrtz(xp[(2 * cp) * 4096], xp[(2 * cp + 1) * 4096]);
        const h2* wqp = s_w + 1024 + h * 256;
        #pragma unroll
        for (int cp = 0; cp < 16; ++cp) {
            h2 xv = xv2[cp];
            const uint4* wqr = (const uint4*)(wqp + cp * 16);
            uint4 qw[4] = { wqr[0], wqr[1], wqr[2], wqr[3] };
            const unsigned* qwu = (const unsigned*)qw;
            #pragma unroll
            for (int co = 0; co < 16; ++co)
                accQ[co] = dot2u(qwu[co], xv, accQ[co]);
        }
    }

    // ---- qe[7] = q . emb, pair-combined via DPP ----
    float qe[KK];
    #pragma unroll
    for (int t = 0; t < KK; ++t) {
        float a = 0.f;
        #pragma unroll
        for (int c = 0; c < 16; ++c)
            a = fmaf(accQ[c], s_emb[(h * 16 + c) * KK + t], a);
        qe[t] = a + 0.f;
    }
    #pragma unroll
    for (int t = 0; t < KK; ++t)
        qe[t] += pswap(qe[t]);

    // ---- pack q to f16 pairs ----
    h2 q2[8];
    #pragma unroll
    for (int j = 0; j < 8; ++j) q2[j] = pkrtz(accQ[2 * j], accQ[2 * j + 1]);

    __syncthreads();   // s_ku / s_vu complete

    const int rowsel = (g < 4) ? 1 : 0;

    // ---- Phase A: 49 logits, 2 positions in flight, DPP pair-combine ----
    float lg[K2];
    const unsigned* kb = s_ku + h * 8;
    #pragma unroll
    for (int tp = 0; tp < 24; ++tp) {
        const int t0 = 2 * tp, t1 = t0 + 1;
        const int ki0 = t0 / KK, kj0 = t0 - ki0 * KK;
        const int ki1 = t1 / KK, kj1 = t1 - ki1 * KK;
        const uint2* kp0 = (const uint2*)(kb + ((ty + ki0) * HS + tx + kj0) * KDW);
        const uint2* kp1 = (const uint2*)(kb + ((ty + ki1) * HS + tx + kj1) * KDW);
        uint2 a0 = kp0[0], a1 = kp0[1], a2 = kp0[2], a3 = kp0[3];
        uint2 b0 = kp1[0], b1 = kp1[1], b2 = kp1[2], b3 = kp1[3];
        float p0 = 0.f, p1 = 0.f;
        p0 = dot2u(a0.x, q2[0], p0);  p1 = dot2u(b0.x, q2[0], p1);
        p0 = dot2u(a0.y, q2[1], p0);  p1 = dot2u(b0.y, q2[1], p1);
        p0 = dot2u(a1.x, q2[2], p0);  p1 = dot2u(b1.x, q2[2], p1);
        p0 = dot2u(a1.y, q2[3], p0);  p1 = dot2u(b1.y, q2[3], p1);
        p0 = dot2u(a2.x, q2[4], p0);  p1 = dot2u(b2.x, q2[4], p1);
        p0 = dot2u(a2.y, q2[5], p0);  p1 = dot2u(b2.y, q2[5], p1);
        p0 = dot2u(a3.x, q2[6], p0);  p1 = dot2u(b3.x, q2[6], p1);
        p0 = dot2u(a3.y, q2[7], p0);  p1 = dot2u(b3.y, q2[7], p1);
        lg[t0] = p0 + pswap(p0) + (rowsel ? qe[ki0] : qe[kj0]);
        lg[t1] = p1 + pswap(p1) + (rowsel ? qe[ki1] : qe[kj1]);
    }
    {   // t = 48 (ki=6, kj=6)
        const uint2* kp = (const uint2*)(kb + ((ty + 6) * HS + tx + 6) * KDW);
        uint2 a0 = kp[0], a1 = kp[1], a2 = kp[2], a3 = kp[3];
        float p0 = 0.f;
        p0 = dot2u(a0.x, q2[0], p0); p0 = dot2u(a0.y, q2[1], p0);
        p0 = dot2u(a1.x, q2[2], p0); p0 = dot2u(a1.y, q2[3], p0);
        p0 = dot2u(a2.x, q2[4], p0); p0 = dot2u(a2.y, q2[5], p0);
        p0 = dot2u(a3.x, q2[6], p0); p0 = dot2u(a3.y, q2[7], p0);
        lg[48] = p0 + pswap(p0) + qe[6];
    }

    // ---- Phase B: tree max, independent exps, tree sum ----
    float m0 = lg[0], m1 = lg[1], m2 = lg[2], m3 = lg[3];
    #pragma unroll
    for (int t = 4; t < 48; t += 4) {
        m0 = fmaxf(m0, lg[t]);
        m1 = fmaxf(m1, lg[t + 1]);
        m2 = fmaxf(m2, lg[t + 2]);
        m3 = fmaxf(m3, lg[t + 3]);
    }
    const float mx = fmaxf(fmaxf(m0, m1), fmaxf(m2, fmaxf(m3, lg[48])));

    float s0 = 0.f, s1 = 0.f, s2 = 0.f, s3 = 0.f;
    #pragma unroll
    for (int t = 0; t < K2; ++t) {
        float pe = __expf(lg[t] - mx);
        lg[t] = pe;
        if ((t & 3) == 0) s0 += pe;
        else if ((t & 3) == 1) s1 += pe;
        else if ((t & 3) == 2) s2 += pe;
        else s3 += pe;
    }
    const float s = (s0 + s1) + (s2 + s3);

    // ---- PV: 2 positions in flight, pure f16 fma accumulation ----
    __half2 o2[8];
    #pragma unroll
    for (int j = 0; j < 8; ++j) o2[j] = __float2half2_rn(0.f);

    const unsigned* vb = s_vu + h * 8;
    #pragma unroll
    for (int tp = 0; tp < 24; ++tp) {
        const int t0 = 2 * tp, t1 = t0 + 1;
        const int ki0 = t0 / KK, kj0 = t0 - ki0 * KK;
        const int ki1 = t1 / KK, kj1 = t1 - ki1 * KK;
        const uint2* vp0 = (const uint2*)(vb + ((ty + ki0) * HS + tx + kj0) * KDW);
        const uint2* vp1 = (const uint2*)(vb + ((ty + ki1) * HS + tx + kj1) * KDW);
        uint2 a0 = vp0[0], a1 = vp0[1], a2 = vp0[2], a3 = vp0[3];
        uint2 b0 = vp1[0], b1 = vp1[1], b2 = vp1[2], b3 = vp1[3];
        const __half2 pe0 = __float2half2_rn(lg[t0]);
        const __half2 pe1 = __float2half2_rn(lg[t1]);
        U32H c0, c1, c2, c3, c4, c5, c6, c7;
        c0.u = a0.x; c1.u = a0.y; c2.u = a1.x; c3.u = a1.y;
        c4.u = a2.x; c5.u = a2.y; c6.u = a3.x; c7.u = a3.y;
        o2[0] = __hfma2(c0.p, pe0, o2[0]);
        o2[1] = __hfma2(c1.p, pe0, o2[1]);
        o2[2] = __hfma2(c2.p, pe0, o2[2]);
        o2[3] = __hfma2(c3.p, pe0, o2[3]);
        o2[4] = __hfma2(c4.p, pe0, o2[4]);
        o2[5] = __hfma2(c5.p, pe0, o2[5]);
        o2[6] = __hfma2(c6.p, pe0, o2[6]);
        o2[7] = __hfma2(c7.p, pe0, o2[7]);
        c0.u = b0.x; c1.u = b0.y; c2.u = b1.x; c3.u = b1.y;
        c4.u = b2.x; c5.u = b2.y; c6.u = b3.x; c7.u = b3.y;
        o2[0] = __hfma2(c0.p, pe1, o2[0]);
        o2[1] = __hfma2(c1.p, pe1, o2[1]);
        o2[2] = __hfma2(c2.p, pe1, o2[2]);
        o2[3] = __hfma2(c3.p, pe1, o2[3]);
        o2[4] = __hfma2(c4.p, pe1, o2[4]);
        o2[5] = __hfma2(c5.p, pe1, o2[5]);
        o2[6] = __hfma2(c6.p, pe1, o2[6]);
        o2[7] = __hfma2(c7.p, pe1, o2[7]);
    }
    {   // t = 48
        const uint2* vp = (const uint2*)(vb + ((ty + 6) * HS + tx + 6) * KDW);
        uint2 a0 = vp[0], a1 = vp[1], a2 = vp[2], a3 = vp[3];
        const __half2 pe0 = __float2half2_rn(lg[48]);
        U32H c0, c1, c2, c3, c4, c5, c6, c7;
        c0.u = a0.x; c1.u = a0.y; c2.u = a1.x; c3.u = a1.y;
        c4.u = a2.x; c5.u = a2.y; c6.u = a3.x; c7.u = a3.y;
        o2[0] = __hfma2(c0.p, pe0, o2[0]);
        o2[1] = __hfma2(c1.p, pe0, o2[1]);
        o2[2] = __hfma2(c2.p, pe0, o2[2]);
        o2[3] = __hfma2(c3.p, pe0, o2[3]);
        o2[4] = __hfma2(c4.p, pe0, o2[4]);
        o2[5] = __hfma2(c5.p, pe0, o2[5]);
        o2[6] = __hfma2(c6.p, pe0, o2[6]);
        o2[7] = __hfma2(c7.p, pe0, o2[7]);
    }

    // ---- write 16 channels ----
    const float inv = 1.0f / s;
    float* op = out + (size_t)(b * 256 + g * 32 + h * 16) * 4096 + yy * 64 + xx;
    #pragma unroll
    for (int j = 0; j < 8; ++j) {
        float2 f = __half22float2(o2[j]);
        op[(2 * j) * 4096]     = f.x * inv;
        op[(2 * j + 1) * 4096] = f.y * inv;
    }
}

extern "C" void kernel_launch(void* const* d_in, const int* in_sizes, int n_in,
                              void* d_out, int out_size, void* d_ws, size_t ws_size,
                              hipStream_t stream) {
    const float* x       = (const float*)d_in[0];
    const float* wq      = (const float*)d_in[1];
    const float* wk      = (const float*)d_in[2];
    const float* wv      = (const float*)d_in[3];
    const float* row_emb = (const float*)d_in[4];
    const float* col_emb = (const float*)d_in[5];
    float* out = (float*)d_out;

    dim3 grid(4, 4, 32);   // remapped inside kernel (XCD-bijective swizzle)
    dim3 block(512);
    sasa_fused_kernel<<<grid, block, 0, stream>>>(x, wq, wk, wv, row_emb, col_emb, out);
}

// Round 27
// 40.058 us; speedup vs baseline: 7.7628x; 1.3566x over previous
//
#include <hip/hip_runtime.h>
#include <hip/hip_bf16.h>
#include <hip/hip_fp16.h>

// SASA local self-attention, fused. Round 27: MFMA K/V halo projection.
//  - K/V projection (484 px x 64 outch x K=32) via mfma_f32_16x16x32_f16:
//    31 pixel-tiles x 4 MFMAs/block replaces ~1024 dot2/thread (~18us VALU).
//  - fragment mapping: A row=lane&15,k=(lane>>4)*8+j ; B k=...,col=lane&15 ;
//    D col=lane&15,row=(lane>>4)*4+reg (guide-verified C/D).
//  - D stored to the existing KDW=18 layout via 2-byte LDS writes.
//  - Q-projection / qe / attention byte-identical to r16 (best-known 49.9us).
// B=4, CIN=COUT=256, H=W=64, G=8, CG=32, K=7, PAD=3.
#define TS   16
#define HS   22
#define HP   484
#define KDW  18          // u32 stride per halo pixel (72B)
#define KK   7
#define K2   49

typedef _Float16 h2   __attribute__((ext_vector_type(2)));
typedef _Float16 f16x8 __attribute__((ext_vector_type(8)));
typedef float    f32x4 __attribute__((ext_vector_type(4)));
union U32H { unsigned u; h2 h; __half2 p; };

__device__ __forceinline__ h2 pkrtz(float a, float b) {
    auto r = __builtin_amdgcn_cvt_pkrtz(a, b);
    union { decltype(r) i; h2 o; } c; c.i = r;
    return c.o;
}
__device__ __forceinline__ float dot2(h2 a, h2 b, float c) {
#if __has_builtin(__builtin_amdgcn_fdot2)
    return __builtin_amdgcn_fdot2(a, b, c, false);
#else
    return fmaf((float)a.x, (float)b.x, fmaf((float)a.y, (float)b.y, c));
#endif
}
__device__ __forceinline__ float dot2u(unsigned wu, h2 b, float c) {
    U32H w; w.u = wu; return dot2(w.h, b, c);
}
__device__ __forceinline__ float pswap(float v) {
#if __has_builtin(__builtin_amdgcn_mov_dpp)
    int j = __builtin_amdgcn_mov_dpp(__float_as_int(v), 0xB1, 0xF, 0xF, true);
    return __int_as_float(j);
#else
    return __shfl_xor(v, 1, 64);
#endif
}

__global__ __attribute__((amdgpu_flat_work_group_size(512, 512), amdgpu_waves_per_eu(4, 4)))
void sasa_fused_kernel(const float* __restrict__ x,
                       const float* __restrict__ wq,
                       const float* __restrict__ wk,
                       const float* __restrict__ wv,
                       const float* __restrict__ row_emb,
                       const float* __restrict__ col_emb,
                       float* __restrict__ out)
{
    __shared__ h2       s_w[1536];         // [m(k,v,q)*2+hh][cp][co], 6 KB
    __shared__ float    s_emb[224];        // E[c][t], 0.9 KB
    __shared__ unsigned s_ku[HP * KDW];    // K halo, f16 pairs, 34.8 KB
    __shared__ unsigned s_vu[HP * KDW];    // V halo, f16 pairs, 34.8 KB

    const int tid = threadIdx.x;

    // ---- XCD-bijective swizzle (r15) ----
    const int lin  = blockIdx.x + (blockIdx.y << 2) + (blockIdx.z << 4);
    const int xcd  = lin & 7;
    const int slot = lin >> 3;
    const int zg   = xcd + ((slot >> 4) << 3);
    const int sp   = slot & 15;
    const int b    = zg >> 3;
    const int g    = zg & 7;
    const int y0   = (sp >> 2) * TS;
    const int x0   = (sp & 3) * TS;

    const float* xg = x + (size_t)(b * 256 + g * 32) * 4096;

    // ---- stage all 3 weight matrices as f16 pairs + emb slice ----
    {
        const int cp  = tid & 15;
        const int cog = tid >> 4;
        const int hh  = cog >> 4;
        const int co  = cog & 15;
        const int di  = (hh * 16 + cp) * 16 + co;
        const float2* wk2 = (const float2*)(wk + g * 1024);
        const float2* wv2 = (const float2*)(wv + g * 1024);
        const float2* wq2 = (const float2*)(wq + g * 1024);
        float2 a = wk2[tid]; s_w[di]        = pkrtz(a.x, a.y);
        float2 v = wv2[tid]; s_w[512 + di]  = pkrtz(v.x, v.y);
        float2 q = wq2[tid]; s_w[1024 + di] = pkrtz(q.x, q.y);
    }
    if (tid < 224) {
        int c = tid / KK, t = tid - c * KK;
        s_emb[tid] = (g < 4) ? row_emb[(g * 32 + c) * KK + t]
                             : col_emb[((g - 4) * 32 + c) * KK + t];
    }
    __syncthreads();

    // ---- K/V halo projection via MFMA (wave-tiled) ----
    {
        const int lane = tid & 63;
        const int wid  = tid >> 6;        // 0..7
        const int lrow = lane & 15;       // A row / B col / D col
        const int lgrp = lane >> 4;       // k group 0..3

        // B fragments: B[k=(lgrp*8+i)][col=lrow] = w[col_global][k]
        f16x8 bk0, bk1, bv0, bv1;
        #pragma unroll
        for (int j = 0; j < 4; ++j) {
            const int cp = lgrp * 4 + j;  // cin pair index
            h2 pk0 = s_w[(0 * 16 + cp) * 16 + lrow];          // wk, hh=0
            h2 pk1 = s_w[(1 * 16 + cp) * 16 + lrow];          // wk, hh=1
            h2 pv0 = s_w[512 + (0 * 16 + cp) * 16 + lrow];    // wv, hh=0
            h2 pv1 = s_w[512 + (1 * 16 + cp) * 16 + lrow];    // wv, hh=1
            bk0[2 * j] = pk0.x; bk0[2 * j + 1] = pk0.y;
            bk1[2 * j] = pk1.x; bk1[2 * j + 1] = pk1.y;
            bv0[2 * j] = pv0.x; bv0[2 * j + 1] = pv0.y;
            bv1[2 * j] = pv1.x; bv1[2 * j + 1] = pv1.y;
        }

        _Float16* sk16 = (_Float16*)s_ku;
        _Float16* sv16 = (_Float16*)s_vu;
        const f32x4 zero = {0.f, 0.f, 0.f, 0.f};

        #pragma unroll 1
        for (int t = wid; t < 31; t += 8) {
            const int hp = t * 16 + lrow;     // this lane's A row (pixel)
            f16x8 a;
            bool valid = false;
            int gy = 0, gx = 0;
            if (hp < HP) {
                const int hy = hp / HS, hx = hp - hy * HS;
                gy = y0 + hy - 3; gx = x0 + hx - 3;
                valid = ((unsigned)gy < 64u) && ((unsigned)gx < 64u);
            }
            if (valid) {
                const float* xp = xg + gy * 64 + gx + (size_t)(lgrp * 8) * 4096;
                #pragma unroll
                for (int i2 = 0; i2 < 4; ++i2) {
                    h2 pr = pkrtz(xp[(2 * i2) * 4096], xp[(2 * i2 + 1) * 4096]);
                    a[2 * i2] = pr.x; a[2 * i2 + 1] = pr.y;
                }
            } else {
                #pragma unroll
                for (int i = 0; i < 8; ++i) a[i] = (_Float16)0.f;
            }

            f32x4 dk0 = __builtin_amdgcn_mfma_f32_16x16x32_f16(a, bk0, zero, 0, 0, 0);
            f32x4 dk1 = __builtin_amdgcn_mfma_f32_16x16x32_f16(a, bk1, zero, 0, 0, 0);
            f32x4 dv0 = __builtin_amdgcn_mfma_f32_16x16x32_f16(a, bv0, zero, 0, 0, 0);
            f32x4 dv1 = __builtin_amdgcn_mfma_f32_16x16x32_f16(a, bv1, zero, 0, 0, 0);

            // D: row = lgrp*4 + r (pixel), col = lrow (outch)
            #pragma unroll
            for (int r = 0; r < 4; ++r) {
                const int hpo = t * 16 + lgrp * 4 + r;
                if (hpo < HP) {
                    const int base = hpo * 36;         // f16 elems per pixel row
                    sk16[base + lrow]      = (_Float16)dk0[r];
                    sk16[base + 16 + lrow] = (_Float16)dk1[r];
                    sv16[base + lrow]      = (_Float16)dv0[r];
                    sv16[base + 16 + lrow] = (_Float16)dv1[r];
                }
            }
        }
    }

    // ---- q projection: thread (p, h) owns 16 q channels (unchanged r16) ----
    const int p  = tid >> 1;
    const int h  = tid & 1;
    const int tx = p & 15, ty = p >> 4;
    const int yy = y0 + ty, xx = x0 + tx;
    float accQ[16];
    #pragma unroll
    for (int c = 0; c < 16; ++c) accQ[c] = 0.f;
    {
        const float* xp = xg + yy * 64 + xx;
        h2 xv2[16];
        #pragma unroll
        for (int cp = 0; cp < 16; ++cp)
            xv2[cp] = pkrtz(xp[(2 * cp) * 4096], xp[(2 * cp + 1) * 4096]);
        const h2* wqp = s_w + 1024 + h * 256;
        #pragma unroll
        for (int cp = 0; cp < 16; ++cp) {
            h2 xv = xv2[cp];
            const uint4* wqr = (const uint4*)(wqp + cp * 16);
            uint4 qw[4] = { wqr[0], wqr[1], wqr[2], wqr[3] };
            const unsigned* qwu = (const unsigned*)qw;
            #pragma unroll
            for (int co = 0; co < 16; ++co)
                accQ[co] = dot2u(qwu[co], xv, accQ[co]);
        }
    }

    // ---- qe[7] = q . emb, pair-combined via DPP ----
    float qe[KK];
    #pragma unroll
    for (int t = 0; t < KK; ++t) {
        float a = 0.f;
        #pragma unroll
        for (int c = 0; c < 16; ++c)
            a = fmaf(accQ[c], s_emb[(h * 16 + c) * KK + t], a);
        qe[t] = a + 0.f;
    }
    #pragma unroll
    for (int t = 0; t < KK; ++t)
        qe[t] += pswap(qe[t]);

    // ---- pack q to f16 pairs ----
    h2 q2[8];
    #pragma unroll
    for (int j = 0; j < 8; ++j) q2[j] = pkrtz(accQ[2 * j], accQ[2 * j + 1]);

    __syncthreads();   // s_ku / s_vu complete

    const int rowsel = (g < 4) ? 1 : 0;

    // ---- Phase A: 49 logits, 2 positions in flight, DPP pair-combine ----
    float lg[K2];
    const unsigned* kb = s_ku + h * 8;
    #pragma unroll
    for (int tp = 0; tp < 24; ++tp) {
        const int t0 = 2 * tp, t1 = t0 + 1;
        const int ki0 = t0 / KK, kj0 = t0 - ki0 * KK;
        const int ki1 = t1 / KK, kj1 = t1 - ki1 * KK;
        const uint2* kp0 = (const uint2*)(kb + ((ty + ki0) * HS + tx + kj0) * KDW);
        const uint2* kp1 = (const uint2*)(kb + ((ty + ki1) * HS + tx + kj1) * KDW);
        uint2 a0 = kp0[0], a1 = kp0[1], a2 = kp0[2], a3 = kp0[3];
        uint2 b0 = kp1[0], b1 = kp1[1], b2 = kp1[2], b3 = kp1[3];
        float p0 = 0.f, p1 = 0.f;
        p0 = dot2u(a0.x, q2[0], p0);  p1 = dot2u(b0.x, q2[0], p1);
        p0 = dot2u(a0.y, q2[1], p0);  p1 = dot2u(b0.y, q2[1], p1);
        p0 = dot2u(a1.x, q2[2], p0);  p1 = dot2u(b1.x, q2[2], p1);
        p0 = dot2u(a1.y, q2[3], p0);  p1 = dot2u(b1.y, q2[3], p1);
        p0 = dot2u(a2.x, q2[4], p0);  p1 = dot2u(b2.x, q2[4], p1);
        p0 = dot2u(a2.y, q2[5], p0);  p1 = dot2u(b2.y, q2[5], p1);
        p0 = dot2u(a3.x, q2[6], p0);  p1 = dot2u(b3.x, q2[6], p1);
        p0 = dot2u(a3.y, q2[7], p0);  p1 = dot2u(b3.y, q2[7], p1);
        lg[t0] = p0 + pswap(p0) + (rowsel ? qe[ki0] : qe[kj0]);
        lg[t1] = p1 + pswap(p1) + (rowsel ? qe[ki1] : qe[kj1]);
    }
    {   // t = 48 (ki=6, kj=6)
        const uint2* kp = (const uint2*)(kb + ((ty + 6) * HS + tx + 6) * KDW);
        uint2 a0 = kp[0], a1 = kp[1], a2 = kp[2], a3 = kp[3];
        float p0 = 0.f;
        p0 = dot2u(a0.x, q2[0], p0); p0 = dot2u(a0.y, q2[1], p0);
        p0 = dot2u(a1.x, q2[2], p0); p0 = dot2u(a1.y, q2[3], p0);
        p0 = dot2u(a2.x, q2[4], p0); p0 = dot2u(a2.y, q2[5], p0);
        p0 = dot2u(a3.x, q2[6], p0); p0 = dot2u(a3.y, q2[7], p0);
        lg[48] = p0 + pswap(p0) + qe[6];
    }

    // ---- Phase B: tree max, independent exps, tree sum ----
    float m0 = lg[0], m1 = lg[1], m2 = lg[2], m3 = lg[3];
    #pragma unroll
    for (int t = 4; t < 48; t += 4) {
        m0 = fmaxf(m0, lg[t]);
        m1 = fmaxf(m1, lg[t + 1]);
        m2 = fmaxf(m2, lg[t + 2]);
        m3 = fmaxf(m3, lg[t + 3]);
    }
    const float mx = fmaxf(fmaxf(m0, m1), fmaxf(m2, fmaxf(m3, lg[48])));

    float s0 = 0.f, s1 = 0.f, s2 = 0.f, s3 = 0.f;
    #pragma unroll
    for (int t = 0; t < K2; ++t) {
        float pe = __expf(lg[t] - mx);
        lg[t] = pe;
        if ((t & 3) == 0) s0 += pe;
        else if ((t & 3) == 1) s1 += pe;
        else if ((t & 3) == 2) s2 += pe;
        else s3 += pe;
    }
    const float s = (s0 + s1) + (s2 + s3);

    // ---- PV: 2 positions in flight, pure f16 fma accumulation ----
    __half2 o2[8];
    #pragma unroll
    for (int j = 0; j < 8; ++j) o2[j] = __float2half2_rn(0.f);

    const unsigned* vb = s_vu + h * 8;
    #pragma unroll
    for (int tp = 0; tp < 24; ++tp) {
        const int t0 = 2 * tp, t1 = t0 + 1;
        const int ki0 = t0 / KK, kj0 = t0 - ki0 * KK;
        const int ki1 = t1 / KK, kj1 = t1 - ki1 * KK;
        const uint2* vp0 = (const uint2*)(vb + ((ty + ki0) * HS + tx + kj0) * KDW);
        const uint2* vp1 = (const uint2*)(vb + ((ty + ki1) * HS + tx + kj1) * KDW);
        uint2 a0 = vp0[0], a1 = vp0[1], a2 = vp0[2], a3 = vp0[3];
        uint2 b0 = vp1[0], b1 = vp1[1], b2 = vp1[2], b3 = vp1[3];
        const __half2 pe0 = __float2half2_rn(lg[t0]);
        const __half2 pe1 = __float2half2_rn(lg[t1]);
        U32H c0, c1, c2, c3, c4, c5, c6, c7;
        c0.u = a0.x; c1.u = a0.y; c2.u = a1.x; c3.u = a1.y;
        c4.u = a2.x; c5.u = a2.y; c6.u = a3.x; c7.u = a3.y;
        o2[0] = __hfma2(c0.p, pe0, o2[0]);
        o2[1] = __hfma2(c1.p, pe0, o2[1]);
        o2[2] = __hfma2(c2.p, pe0, o2[2]);
        o2[3] = __hfma2(c3.p, pe0, o2[3]);
        o2[4] = __hfma2(c4.p, pe0, o2[4]);
        o2[5] = __hfma2(c5.p, pe0, o2[5]);
        o2[6] = __hfma2(c6.p, pe0, o2[6]);
        o2[7] = __hfma2(c7.p, pe0, o2[7]);
        c0.u = b0.x; c1.u = b0.y; c2.u = b1.x; c3.u = b1.y;
        c4.u = b2.x; c5.u = b2.y; c6.u = b3.x; c7.u = b3.y;
        o2[0] = __hfma2(c0.p, pe1, o2[0]);
        o2[1] = __hfma2(c1.p, pe1, o2[1]);
        o2[2] = __hfma2(c2.p, pe1, o2[2]);
        o2[3] = __hfma2(c3.p, pe1, o2[3]);
        o2[4] = __hfma2(c4.p, pe1, o2[4]);
        o2[5] = __hfma2(c5.p, pe1, o2[5]);
        o2[6] = __hfma2(c6.p, pe1, o2[6]);
        o2[7] = __hfma2(c7.p, pe1, o2[7]);
    }
    {   // t = 48
        const uint2* vp = (const uint2*)(vb + ((ty + 6) * HS + tx + 6) * KDW);
        uint2 a0 = vp[0], a1 = vp[1], a2 = vp[2], a3 = vp[3];
        const __half2 pe0 = __float2half2_rn(lg[48]);
        U32H c0, c1, c2, c3, c4, c5, c6, c7;
        c0.u = a0.x; c1.u = a0.y; c2.u = a1.x; c3.u = a1.y;
        c4.u = a2.x; c5.u = a2.y; c6.u = a3.x; c7.u = a3.y;
        o2[0] = __hfma2(c0.p, pe0, o2[0]);
        o2[1] = __hfma2(c1.p, pe0, o2[1]);
        o2[2] = __hfma2(c2.p, pe0, o2[2]);
        o2[3] = __hfma2(c3.p, pe0, o2[3]);
        o2[4] = __hfma2(c4.p, pe0, o2[4]);
        o2[5] = __hfma2(c5.p, pe0, o2[5]);
        o2[6] = __hfma2(c6.p, pe0, o2[6]);
        o2[7] = __hfma2(c7.p, pe0, o2[7]);
    }

    // ---- write 16 channels ----
    const float inv = 1.0f / s;
    float* op = out + (size_t)(b * 256 + g * 32 + h * 16) * 4096 + yy * 64 + xx;
    #pragma unroll
    for (int j = 0; j < 8; ++j) {
        float2 f = __half22float2(o2[j]);
        op[(2 * j) * 4096]     = f.x * inv;
        op[(2 * j + 1) * 4096] = f.y * inv;
    }
}

extern "C" void kernel_launch(void* const* d_in, const int* in_sizes, int n_in,
                              void* d_out, int out_size, void* d_ws, size_t ws_size,
                              hipStream_t stream) {
    const float* x       = (const float*)d_in[0];
    const float* wq      = (const float*)d_in[1];
    const float* wk      = (const float*)d_in[2];
    const float* wv      = (const float*)d_in[3];
    const float* row_emb = (const float*)d_in[4];
    const float* col_emb = (const float*)d_in[5];
    float* out = (float*)d_out;

    dim3 grid(4, 4, 32);   // remapped inside kernel (XCD-bijective swizzle)
    dim3 block(512);
    sasa_fused_kernel<<<grid, block, 0, stream>>>(x, wq, wk, wv, row_emb, col_emb, out);
}